// Round 3
// baseline (154.450 us; speedup 1.0000x reference)
//
#include <hip/hip_runtime.h>
#include <math.h>

#define Nn 8192
#define Dd 256
#define NBINS 64
#define NSPLIT 8

typedef __attribute__((ext_vector_type(8))) short short8;
typedef __attribute__((ext_vector_type(4))) float f32x4;

#define GLOAD16(g, l)                                                        \
  __builtin_amdgcn_global_load_lds(                                          \
      (const __attribute__((address_space(1))) void*)(g),                    \
      (__attribute__((address_space(3))) void*)(l), 16, 0, 0)

static __device__ __forceinline__ unsigned short f2bf(float f) {
  unsigned int u = __float_as_uint(f);
  u = (u + 0x7fffu + ((u >> 16) & 1u)) >> 16;  // RNE
  return (unsigned short)u;
}
// order-preserving bijection float -> uint (works for negatives; atomicMax/Min on uint)
static __device__ __forceinline__ unsigned int enc_ord(float f) {
  unsigned int u = __float_as_uint(f);
  return (u & 0x80000000u) ? ~u : (u | 0x80000000u);
}
static __device__ __forceinline__ float dec_ord(unsigned int u) {
  unsigned int b = (u & 0x80000000u) ? (u ^ 0x80000000u) : ~u;
  return __uint_as_float(b);
}

// ---------------- K0: bf16 cast + row squared norms (fp32) + init accumulators ----------------
__global__ __launch_bounds__(256) void prep_kernel(const float* __restrict__ x,
                                                   unsigned short* __restrict__ xb,
                                                   float* __restrict__ sq,
                                                   unsigned int* __restrict__ pos2,
                                                   unsigned int* __restrict__ neg2) {
  const int w = threadIdx.x >> 6;
  const int lane = threadIdx.x & 63;
  const int row = blockIdx.x * 4 + w;
  const float4 v = *(const float4*)(x + (size_t)row * Dd + lane * 4);
  ushort4 b;
  b.x = f2bf(v.x); b.y = f2bf(v.y); b.z = f2bf(v.z); b.w = f2bf(v.w);
  *(ushort4*)(xb + (size_t)row * Dd + lane * 4) = b;
  float s = v.x * v.x + v.y * v.y + v.z * v.z + v.w * v.w;
#pragma unroll
  for (int off = 32; off >= 1; off >>= 1) s += __shfl_xor(s, off);
  if (lane == 0) {
    sq[row] = s;
    pos2[row] = 0x007fffffu;  // enc_ord(-inf)
    neg2[row] = 0xff800000u;  // enc_ord(+inf)
  }
}

// stage one half-K B tile (128 cols x 128 k = 32KB) with XOR chunk placement:
// chunk c holds (col=c>>4, kq=(c&15)^(col&15)) -> coalesced global src, conflict-free reads
static __device__ __forceinline__ void stage_half(const unsigned short* __restrict__ xb,
                                                  int c0, int hh, unsigned short* buf, int t) {
#pragma unroll
  for (int i = 0; i < 8; ++i) {
    const int c = i * 256 + t;
    const int col = c >> 4;
    const int kq = (c & 15) ^ (col & 15);
    GLOAD16(xb + (size_t)(c0 + col) * Dd + hh * 128 + kq * 8, buf + (size_t)c * 8);
  }
}

// ---------------- K1: MFMA Gram + fused masked max/min ----------------
// A fragments (64 rows x K=256 per wave) live in 128 VGPRs for the whole block.
// B double-buffered in LDS (2 x 32KB separate arrays), 1 barrier per half-K unit.
__global__ __launch_bounds__(256, 2) void pairwise_kernel(const unsigned short* __restrict__ xb,
                                                          const int* __restrict__ lab,
                                                          const float* __restrict__ sq,
                                                          unsigned int* __restrict__ pos2,
                                                          unsigned int* __restrict__ neg2) {
  __shared__ __align__(16) unsigned short Bs0[2048 * 8];  // 32KB
  __shared__ __align__(16) unsigned short Bs1[2048 * 8];  // 32KB
  __shared__ int lab_s[128];

  const int t = threadIdx.x;
  const int lane = t & 63;
  const int w = t >> 6;
  const int wr = w >> 1, wc = w & 1;
  const int c_l = lane & 15;
  const int kq_l = lane >> 4;
  const int rows0 = blockIdx.x * 128;
  const int cbase = blockIdx.y * (Nn / NSPLIT);

  // prefetch first half-tile, stage row labels
  stage_half(xb, cbase, 0, Bs0, t);
  if (t < 128) lab_s[t] = lab[rows0 + t];

  // A fragments -> registers (whole K), loaded once per block
  short8 af[32];
#pragma unroll
  for (int k2 = 0; k2 < 8; ++k2)
#pragma unroll
    for (int m = 0; m < 4; ++m)
      af[k2 * 4 + m] = *(const short8*)(xb + (size_t)(rows0 + wr * 64 + m * 16 + c_l) * Dd +
                                        k2 * 32 + kq_l * 8);

  const short8* Bv0 = (const short8*)Bs0;
  const short8* Bv1 = (const short8*)Bs1;

#pragma unroll 1
  for (int ct = 0; ct < 8; ++ct) {
    const int c0 = cbase + ct * 128;
    f32x4 acc[4][4];
#pragma unroll
    for (int m = 0; m < 4; ++m)
#pragma unroll
      for (int n = 0; n < 4; ++n) acc[m][n] = (f32x4){0.f, 0.f, 0.f, 0.f};

    // ---- half 0: compute Bs0, prefetch Bs1 ----
    __syncthreads();  // implicit vmcnt(0): Bs0 staged; WAR-protects Bs1
    stage_half(xb, c0, 1, Bs1, t);
#pragma unroll
    for (int ks = 0; ks < 4; ++ks) {
      short8 bf[4];
#pragma unroll
      for (int n = 0; n < 4; ++n) {
        const int cc = wc * 64 + n * 16 + c_l;
        bf[n] = Bv0[cc * 16 + ((ks * 4 + kq_l) ^ c_l)];
      }
#pragma unroll
      for (int m = 0; m < 4; ++m)
#pragma unroll
        for (int n = 0; n < 4; ++n)
          acc[m][n] = __builtin_amdgcn_mfma_f32_16x16x32_bf16(af[ks * 4 + m], bf[n], acc[m][n], 0, 0, 0);
    }

    // ---- half 1: compute Bs1, prefetch next ct's Bs0 ----
    __syncthreads();  // Bs1 staged; WAR-protects Bs0
    if (ct < 7) stage_half(xb, c0 + 128, 0, Bs0, t);
#pragma unroll
    for (int ks = 0; ks < 4; ++ks) {
      short8 bf[4];
#pragma unroll
      for (int n = 0; n < 4; ++n) {
        const int cc = wc * 64 + n * 16 + c_l;
        bf[n] = Bv1[cc * 16 + ((ks * 4 + kq_l) ^ c_l)];
      }
#pragma unroll
      for (int m = 0; m < 4; ++m)
#pragma unroll
        for (int n = 0; n < 4; ++n)
          acc[m][n] = __builtin_amdgcn_mfma_f32_16x16x32_bf16(af[(4 + ks) * 4 + m], bf[n], acc[m][n], 0, 0, 0);
    }

    // ---- epilogue: masked running max/min on g = sq_c - 2*acc (row norm added in finalize) ----
    int labr[16];
#pragma unroll
    for (int m = 0; m < 4; ++m) {
      const int4 l4 = *(const int4*)&lab_s[wr * 64 + m * 16 + kq_l * 4];
      labr[m * 4 + 0] = l4.x; labr[m * 4 + 1] = l4.y; labr[m * 4 + 2] = l4.z; labr[m * 4 + 3] = l4.w;
    }
    float pmax[16], nmin[16];
#pragma unroll
    for (int i = 0; i < 16; ++i) { pmax[i] = -INFINITY; nmin[i] = INFINITY; }
#pragma unroll
    for (int n = 0; n < 4; ++n) {
      const int colg = c0 + wc * 64 + n * 16 + c_l;
      const float sc = sq[colg];
      const int lc = lab[colg];
#pragma unroll
      for (int m = 0; m < 4; ++m)
#pragma unroll
        for (int q = 0; q < 4; ++q) {
          const float g = fmaf(-2.0f, acc[m][n][q], sc);
          if (labr[m * 4 + q] == lc) pmax[m * 4 + q] = fmaxf(pmax[m * 4 + q], g);
          else                       nmin[m * 4 + q] = fminf(nmin[m * 4 + q], g);
        }
    }
#pragma unroll
    for (int i = 0; i < 16; ++i) {
      float p = pmax[i], nn2 = nmin[i];
#pragma unroll
      for (int off = 1; off < 16; off <<= 1) {
        p = fmaxf(p, __shfl_xor(p, off));
        nn2 = fminf(nn2, __shfl_xor(nn2, off));
      }
      if (c_l == 0) {
        const int rowg = rows0 + wr * 64 + (i >> 2) * 16 + kq_l * 4 + (i & 3);
        atomicMax(&pos2[rowg], enc_ord(p));
        atomicMin(&neg2[rowg], enc_ord(nn2));
      }
    }
  }
}

// ---------------- K2: finalize: hv, extremes, per-wave histograms, cdf, loss ----------------
__global__ __launch_bounds__(1024) void finalize_kernel(const unsigned int* __restrict__ pos2,
                                                        const unsigned int* __restrict__ neg2,
                                                        const float* __restrict__ sq,
                                                        float* __restrict__ out) {
  __shared__ float hv_s[Nn];
  __shared__ float rbuf[16];
  __shared__ float rbuf2[16];
  __shared__ float hist_w[16][NBINS];  // per-wave histograms (kills LDS-atomic serialization)
  __shared__ float cdf_s[NBINS];
  __shared__ float s_minv, s_bw;
  const int t = threadIdx.x;
  const int lane = t & 63, wid = t >> 6;

  hist_w[wid][lane] = 0.0f;  // lane < 64 == NBINS; each wave zeroes its own

  float lmax = -INFINITY, lmin = INFINITY;
  for (int i = t; i < Nn; i += 1024) {
    const float s = sq[i];
    const float p2 = fmaxf(s + dec_ord(pos2[i]), 1e-12f);
    const float n2 = fmaxf(s + dec_ord(neg2[i]), 1e-12f);
    const float hv = sqrtf(p2) - sqrtf(n2);
    hv_s[i] = hv;
    lmax = fmaxf(lmax, hv);
    lmin = fminf(lmin, hv);
  }
#pragma unroll
  for (int off = 32; off >= 1; off >>= 1) {
    lmax = fmaxf(lmax, __shfl_xor(lmax, off));
    lmin = fminf(lmin, __shfl_xor(lmin, off));
  }
  if (lane == 0) { rbuf[wid] = lmax; rbuf2[wid] = lmin; }
  __syncthreads();
  if (t == 0) {
    float gmax = rbuf[0], gmin = rbuf2[0];
    for (int w = 1; w < 16; ++w) { gmax = fmaxf(gmax, rbuf[w]); gmin = fminf(gmin, rbuf2[w]); }
    const float maxv = fmaxf(gmax, 2.0f);
    const float minv = fminf(gmin, -2.0f);
    s_minv = minv;
    s_bw = (maxv - minv) / (float)(NBINS - 1);
  }
  __syncthreads();

  const float minv = s_minv, bw = s_bw;
  for (int i = t; i < Nn; i += 1024) {
    const float hv = hv_s[i];
    int lo = (int)floorf((hv - minv) / bw);
    lo = min(max(lo, 0), NBINS - 1);
    const int hi = min(lo + 1, NBINS - 1);
    const float alpha = 1.0f - (hv - minv - (float)lo * bw) / bw;
    atomicAdd(&hist_w[wid][lo], alpha);
    atomicAdd(&hist_w[wid][hi], 1.0f - alpha);
  }
  __syncthreads();

  if (t < NBINS) {
    float h = 0.0f;
#pragma unroll
    for (int w2 = 0; w2 < 16; ++w2) h += hist_w[w2][t];
    float total = h;
#pragma unroll
    for (int off = 32; off >= 1; off >>= 1) total += __shfl_xor(total, off);
    const float hn = h / (total + 1e-6f);
    float s2 = hn;
#pragma unroll
    for (int off = 32; off >= 1; off >>= 1) s2 += __shfl_xor(s2, off);
    const float pdf = hn / s2;
    float c = pdf;
#pragma unroll
    for (int off = 1; off < 64; off <<= 1) {
      const float u = __shfl_up(c, off);
      if (lane >= off) c += u;
    }
    cdf_s[t] = c;
  }
  __syncthreads();

  float acc = 0.0f;
  for (int i = t; i < Nn; i += 1024) {
    const float hv = hv_s[i];
    int lo = (int)floorf((hv - minv) / bw);
    lo = min(max(lo, 0), NBINS - 1);
    acc += cdf_s[lo] * hv;
  }
#pragma unroll
  for (int off = 32; off >= 1; off >>= 1) acc += __shfl_xor(acc, off);
  if (lane == 0) rbuf[wid] = acc;
  __syncthreads();
  if (t == 0) {
    float s = 0.0f;
    for (int w2 = 0; w2 < 16; ++w2) s += rbuf[w2];
    out[0] = s / (float)Nn;
  }
}

// ---------------- launch ----------------
extern "C" void kernel_launch(void* const* d_in, const int* in_sizes, int n_in,
                              void* d_out, int out_size, void* d_ws, size_t ws_size,
                              hipStream_t stream) {
  const float* x = (const float*)d_in[0];
  const int* targets = (const int*)d_in[1];
  float* out = (float*)d_out;

  unsigned short* xb = (unsigned short*)d_ws;  // 4 MB
  char* p = (char*)d_ws + (size_t)Nn * Dd * sizeof(unsigned short);
  float* sq = (float*)p;
  unsigned int* pos2 = (unsigned int*)(p + (size_t)Nn * sizeof(float));
  unsigned int* neg2 = (unsigned int*)(p + 2 * (size_t)Nn * sizeof(float));

  prep_kernel<<<Nn / 4, 256, 0, stream>>>(x, xb, sq, pos2, neg2);
  pairwise_kernel<<<dim3(Nn / 128, NSPLIT), 256, 0, stream>>>(xb, targets, sq, pos2, neg2);
  finalize_kernel<<<1, 1024, 0, stream>>>(pos2, neg2, sq, out);
}

// Round 4
// 142.208 us; speedup vs baseline: 1.0861x; 1.0861x over previous
//
#include <hip/hip_runtime.h>
#include <math.h>

#define Nn 8192
#define Dd 256
#define NBINS 64
#define NSPLIT 8

typedef __attribute__((ext_vector_type(8))) short short8;
typedef __attribute__((ext_vector_type(4))) float f32x4;

#define GLOAD16(g, l)                                                        \
  __builtin_amdgcn_global_load_lds(                                          \
      (const __attribute__((address_space(1))) void*)(g),                    \
      (__attribute__((address_space(3))) void*)(l), 16, 0, 0)

static __device__ __forceinline__ unsigned short f2bf(float f) {
  unsigned int u = __float_as_uint(f);
  u = (u + 0x7fffu + ((u >> 16) & 1u)) >> 16;  // RNE
  return (unsigned short)u;
}
// order-preserving bijection float -> uint (atomicMax/Min on uint handles negatives)
static __device__ __forceinline__ unsigned int enc_ord(float f) {
  unsigned int u = __float_as_uint(f);
  return (u & 0x80000000u) ? ~u : (u | 0x80000000u);
}
static __device__ __forceinline__ float dec_ord(unsigned int u) {
  unsigned int b = (u & 0x80000000u) ? (u ^ 0x80000000u) : ~u;
  return __uint_as_float(b);
}

// ---------------- K0: bf16 cast + row squared norms (fp32) + init accumulators ----------------
__global__ __launch_bounds__(256) void prep_kernel(const float* __restrict__ x,
                                                   unsigned short* __restrict__ xb,
                                                   float* __restrict__ sq,
                                                   unsigned int* __restrict__ pos2,
                                                   unsigned int* __restrict__ neg2) {
  const int w = threadIdx.x >> 6;
  const int lane = threadIdx.x & 63;
  const int row = blockIdx.x * 4 + w;
  const float4 v = *(const float4*)(x + (size_t)row * Dd + lane * 4);
  ushort4 b;
  b.x = f2bf(v.x); b.y = f2bf(v.y); b.z = f2bf(v.z); b.w = f2bf(v.w);
  *(ushort4*)(xb + (size_t)row * Dd + lane * 4) = b;
  float s = v.x * v.x + v.y * v.y + v.z * v.z + v.w * v.w;
#pragma unroll
  for (int off = 32; off >= 1; off >>= 1) s += __shfl_xor(s, off);
  if (lane == 0) {
    sq[row] = s;
    pos2[row] = 0x007fffffu;  // enc_ord(-inf)
    neg2[row] = 0xff800000u;  // enc_ord(+inf)
  }
}

// stage one half-K tile (128 rows/cols x 128 k = 32KB) with XOR chunk placement:
// chunk c holds (col=c>>4, kq=(c&15)^(col&15)) -> coalesced global src, conflict-free reads
static __device__ __forceinline__ void stage_half(const unsigned short* __restrict__ xb,
                                                  int c0, int hh, unsigned short* buf, int t) {
#pragma unroll
  for (int i = 0; i < 8; ++i) {
    const int c = i * 256 + t;
    const int col = c >> 4;
    const int kq = (c & 15) ^ (col & 15);
    GLOAD16(xb + (size_t)(c0 + col) * Dd + hh * 128 + kq * 8, buf + (size_t)c * 8);
  }
}

// ---------------- K1: MFMA Gram + fused masked max/min ----------------
// A staged to LDS once, fragments loaded to 128 VGPRs (forced residency: the LDS
// region is then reused as the B double-buffer, so the compiler cannot remat).
// Running pmax/nmin in registers across all col-tiles; one reduce+atomic at end.
__global__ __launch_bounds__(256, 2) void pairwise_kernel(const unsigned short* __restrict__ xb,
                                                          const int* __restrict__ lab,
                                                          const float* __restrict__ sq,
                                                          unsigned int* __restrict__ pos2,
                                                          unsigned int* __restrict__ neg2) {
  __shared__ __align__(16) unsigned short Us[4096 * 8];  // 64KB: A staging, then B dbuf
  __shared__ int lab_s[128];

  const int t = threadIdx.x;
  const int lane = t & 63;
  const int w = t >> 6;
  const int wr = w >> 1, wc = w & 1;
  const int c_l = lane & 15;
  const int kq_l = lane >> 4;
  const int rows0 = blockIdx.x * 128;
  const int cbase = blockIdx.y * (Nn / NSPLIT);

  // ---- stage A (both K halves) into Us, once, coalesced ----
  stage_half(xb, rows0, 0, Us, t);
  stage_half(xb, rows0, 1, Us + 2048 * 8, t);
  if (t < 128) lab_s[t] = lab[rows0 + t];
  __syncthreads();  // A staged (implicit vmcnt(0))

  // ---- A fragments -> registers for the whole kernel ----
  const short8* Uv = (const short8*)Us;
  short8 af[32];
#pragma unroll
  for (int k2 = 0; k2 < 8; ++k2)
#pragma unroll
    for (int m = 0; m < 4; ++m) {
      const int kqf = k2 * 4 + kq_l;               // global k-octet 0..31
      const int rl = wr * 64 + m * 16 + c_l;       // local row 0..127
      af[k2 * 4 + m] = Uv[(kqf >> 4) * 2048 + rl * 16 + ((kqf & 15) ^ (rl & 15))];
    }
  __syncthreads();  // all af reads done before B staging overwrites Us

  unsigned short* Bs0 = Us;
  unsigned short* Bs1 = Us + 2048 * 8;
  const short8* Bv0 = (const short8*)Bs0;
  const short8* Bv1 = (const short8*)Bs1;

  stage_half(xb, cbase, 0, Bs0, t);  // prefetch first half-tile

  float pmax[16], nmin[16];
#pragma unroll
  for (int i = 0; i < 16; ++i) { pmax[i] = -INFINITY; nmin[i] = INFINITY; }

#pragma unroll 1
  for (int ct = 0; ct < 8; ++ct) {
    const int c0 = cbase + ct * 128;
    f32x4 acc[4][4];
#pragma unroll
    for (int m = 0; m < 4; ++m)
#pragma unroll
      for (int n = 0; n < 4; ++n) acc[m][n] = (f32x4){0.f, 0.f, 0.f, 0.f};

    // ---- half 0: compute Bs0, prefetch Bs1 ----
    __syncthreads();  // Bs0 staged; WAR-protects Bs1
    stage_half(xb, c0, 1, Bs1, t);
#pragma unroll
    for (int ks = 0; ks < 4; ++ks) {
      short8 bf[4];
#pragma unroll
      for (int n = 0; n < 4; ++n) {
        const int cc = wc * 64 + n * 16 + c_l;
        bf[n] = Bv0[cc * 16 + ((ks * 4 + kq_l) ^ (cc & 15))];
      }
#pragma unroll
      for (int m = 0; m < 4; ++m)
#pragma unroll
        for (int n = 0; n < 4; ++n)
          acc[m][n] = __builtin_amdgcn_mfma_f32_16x16x32_bf16(af[ks * 4 + m], bf[n], acc[m][n], 0, 0, 0);
    }

    // ---- half 1: compute Bs1, prefetch next ct's Bs0 ----
    __syncthreads();  // Bs1 staged; WAR-protects Bs0
    if (ct < 7) stage_half(xb, c0 + 128, 0, Bs0, t);
#pragma unroll
    for (int ks = 0; ks < 4; ++ks) {
      short8 bf[4];
#pragma unroll
      for (int n = 0; n < 4; ++n) {
        const int cc = wc * 64 + n * 16 + c_l;
        bf[n] = Bv1[cc * 16 + ((ks * 4 + kq_l) ^ (cc & 15))];
      }
#pragma unroll
      for (int m = 0; m < 4; ++m)
#pragma unroll
        for (int n = 0; n < 4; ++n)
          acc[m][n] = __builtin_amdgcn_mfma_f32_16x16x32_bf16(af[(4 + ks) * 4 + m], bf[n], acc[m][n], 0, 0, 0);
    }

    // ---- epilogue: update running masked max/min (registers only) ----
#pragma unroll
    for (int n = 0; n < 4; ++n) {
      const int colg = c0 + wc * 64 + n * 16 + c_l;
      const float sc = sq[colg];
      const int lc = lab[colg];
#pragma unroll
      for (int m = 0; m < 4; ++m) {
#pragma unroll
        for (int q = 0; q < 4; ++q) {
          const float g = fmaf(-2.0f, acc[m][n][q], sc);
          const bool same = (lab_s[wr * 64 + m * 16 + kq_l * 4 + q] == lc);
          pmax[m * 4 + q] = same ? fmaxf(pmax[m * 4 + q], g) : pmax[m * 4 + q];
          nmin[m * 4 + q] = same ? nmin[m * 4 + q] : fminf(nmin[m * 4 + q], g);
        }
      }
    }
  }

  // ---- reduce over the 16 col-lanes, then 2 atomics per row per block ----
#pragma unroll
  for (int i = 0; i < 16; ++i) {
    float p = pmax[i], nn2 = nmin[i];
#pragma unroll
    for (int off = 1; off < 16; off <<= 1) {
      p = fmaxf(p, __shfl_xor(p, off));
      nn2 = fminf(nn2, __shfl_xor(nn2, off));
    }
    if (c_l == 0) {
      const int rowg = rows0 + wr * 64 + (i >> 2) * 16 + kq_l * 4 + (i & 3);
      atomicMax(&pos2[rowg], enc_ord(p));
      atomicMin(&neg2[rowg], enc_ord(nn2));
    }
  }
}

// ---------------- K2: finalize: hv, extremes, per-wave histograms, cdf, loss ----------------
__global__ __launch_bounds__(1024) void finalize_kernel(const unsigned int* __restrict__ pos2,
                                                        const unsigned int* __restrict__ neg2,
                                                        const float* __restrict__ sq,
                                                        float* __restrict__ out) {
  __shared__ float hv_s[Nn];
  __shared__ float rbuf[16];
  __shared__ float rbuf2[16];
  __shared__ float hist_w[16][NBINS];
  __shared__ float cdf_s[NBINS];
  __shared__ float s_minv, s_bw;
  const int t = threadIdx.x;
  const int lane = t & 63, wid = t >> 6;

  hist_w[wid][lane] = 0.0f;

  float lmax = -INFINITY, lmin = INFINITY;
  for (int i = t; i < Nn; i += 1024) {
    const float s = sq[i];
    const float p2 = fmaxf(s + dec_ord(pos2[i]), 1e-12f);
    const float n2 = fmaxf(s + dec_ord(neg2[i]), 1e-12f);
    const float hv = sqrtf(p2) - sqrtf(n2);
    hv_s[i] = hv;
    lmax = fmaxf(lmax, hv);
    lmin = fminf(lmin, hv);
  }
#pragma unroll
  for (int off = 32; off >= 1; off >>= 1) {
    lmax = fmaxf(lmax, __shfl_xor(lmax, off));
    lmin = fminf(lmin, __shfl_xor(lmin, off));
  }
  if (lane == 0) { rbuf[wid] = lmax; rbuf2[wid] = lmin; }
  __syncthreads();
  if (t == 0) {
    float gmax = rbuf[0], gmin = rbuf2[0];
    for (int w = 1; w < 16; ++w) { gmax = fmaxf(gmax, rbuf[w]); gmin = fminf(gmin, rbuf2[w]); }
    const float maxv = fmaxf(gmax, 2.0f);
    const float minv = fminf(gmin, -2.0f);
    s_minv = minv;
    s_bw = (maxv - minv) / (float)(NBINS - 1);
  }
  __syncthreads();

  const float minv = s_minv, bw = s_bw;
  for (int i = t; i < Nn; i += 1024) {
    const float hv = hv_s[i];
    int lo = (int)floorf((hv - minv) / bw);
    lo = min(max(lo, 0), NBINS - 1);
    const int hi = min(lo + 1, NBINS - 1);
    const float alpha = 1.0f - (hv - minv - (float)lo * bw) / bw;
    atomicAdd(&hist_w[wid][lo], alpha);
    atomicAdd(&hist_w[wid][hi], 1.0f - alpha);
  }
  __syncthreads();

  if (t < NBINS) {
    float h = 0.0f;
#pragma unroll
    for (int w2 = 0; w2 < 16; ++w2) h += hist_w[w2][t];
    float total = h;
#pragma unroll
    for (int off = 32; off >= 1; off >>= 1) total += __shfl_xor(total, off);
    const float hn = h / (total + 1e-6f);
    float s2 = hn;
#pragma unroll
    for (int off = 32; off >= 1; off >>= 1) s2 += __shfl_xor(s2, off);
    const float pdf = hn / s2;
    float c = pdf;
#pragma unroll
    for (int off = 1; off < 64; off <<= 1) {
      const float u = __shfl_up(c, off);
      if (lane >= off) c += u;
    }
    cdf_s[t] = c;
  }
  __syncthreads();

  float acc = 0.0f;
  for (int i = t; i < Nn; i += 1024) {
    const float hv = hv_s[i];
    int lo = (int)floorf((hv - minv) / bw);
    lo = min(max(lo, 0), NBINS - 1);
    acc += cdf_s[lo] * hv;
  }
#pragma unroll
  for (int off = 32; off >= 1; off >>= 1) acc += __shfl_xor(acc, off);
  if (lane == 0) rbuf[wid] = acc;
  __syncthreads();
  if (t == 0) {
    float s = 0.0f;
    for (int w2 = 0; w2 < 16; ++w2) s += rbuf[w2];
    out[0] = s / (float)Nn;
  }
}

// ---------------- launch ----------------
extern "C" void kernel_launch(void* const* d_in, const int* in_sizes, int n_in,
                              void* d_out, int out_size, void* d_ws, size_t ws_size,
                              hipStream_t stream) {
  const float* x = (const float*)d_in[0];
  const int* targets = (const int*)d_in[1];
  float* out = (float*)d_out;

  unsigned short* xb = (unsigned short*)d_ws;  // 4 MB
  char* p = (char*)d_ws + (size_t)Nn * Dd * sizeof(unsigned short);
  float* sq = (float*)p;
  unsigned int* pos2 = (unsigned int*)(p + (size_t)Nn * sizeof(float));
  unsigned int* neg2 = (unsigned int*)(p + 2 * (size_t)Nn * sizeof(float));

  prep_kernel<<<Nn / 4, 256, 0, stream>>>(x, xb, sq, pos2, neg2);
  pairwise_kernel<<<dim3(Nn / 128, NSPLIT), 256, 0, stream>>>(xb, targets, sq, pos2, neg2);
  finalize_kernel<<<1, 1024, 0, stream>>>(pos2, neg2, sq, out);
}

// Round 5
// 95.891 us; speedup vs baseline: 1.6107x; 1.4830x over previous
//
#include <hip/hip_runtime.h>
#include <math.h>

#define Nn 8192
#define Dd 256
#define NBINS 64
#define NSPLIT 8

typedef __attribute__((ext_vector_type(8))) short short8;
typedef __attribute__((ext_vector_type(4))) float f32x4;

#define GLOAD16(g, l)                                                        \
  __builtin_amdgcn_global_load_lds(                                          \
      (const __attribute__((address_space(1))) void*)(g),                    \
      (__attribute__((address_space(3))) void*)(l), 16, 0, 0)

static __device__ __forceinline__ unsigned short f2bf(float f) {
  unsigned int u = __float_as_uint(f);
  u = (u + 0x7fffu + ((u >> 16) & 1u)) >> 16;  // RNE
  return (unsigned short)u;
}
// order-preserving bijection float -> uint (atomicMax/Min on uint handles negatives)
static __device__ __forceinline__ unsigned int enc_ord(float f) {
  unsigned int u = __float_as_uint(f);
  return (u & 0x80000000u) ? ~u : (u | 0x80000000u);
}
static __device__ __forceinline__ float dec_ord(unsigned int u) {
  unsigned int b = (u & 0x80000000u) ? (u ^ 0x80000000u) : ~u;
  return __uint_as_float(b);
}

// ---------------- K0: bf16 cast + row squared norms (fp32) + init accumulators ----------------
__global__ __launch_bounds__(256) void prep_kernel(const float* __restrict__ x,
                                                   unsigned short* __restrict__ xb,
                                                   float* __restrict__ sq,
                                                   unsigned int* __restrict__ pos2,
                                                   unsigned int* __restrict__ neg2) {
  const int w = threadIdx.x >> 6;
  const int lane = threadIdx.x & 63;
  const int row = blockIdx.x * 4 + w;
  const float4 v = *(const float4*)(x + (size_t)row * Dd + lane * 4);
  ushort4 b;
  b.x = f2bf(v.x); b.y = f2bf(v.y); b.z = f2bf(v.z); b.w = f2bf(v.w);
  *(ushort4*)(xb + (size_t)row * Dd + lane * 4) = b;
  float s = v.x * v.x + v.y * v.y + v.z * v.z + v.w * v.w;
#pragma unroll
  for (int off = 32; off >= 1; off >>= 1) s += __shfl_xor(s, off);
  if (lane == 0) {
    sq[row] = s;
    pos2[row] = 0x007fffffu;  // enc_ord(-inf)
    neg2[row] = 0xff800000u;  // enc_ord(+inf)
  }
}

// stage one half-K tile (128 rows x 128 k = 32KB) with XOR chunk placement, 512 threads:
// chunk c holds (col=c>>4, kq=(c&15)^(col&15)) -> coalesced global src, conflict-free reads
static __device__ __forceinline__ void stage_half(const unsigned short* __restrict__ xb,
                                                  int c0, int hh, unsigned short* buf, int t) {
#pragma unroll
  for (int i = 0; i < 4; ++i) {
    const int c = i * 512 + t;
    const int col = c >> 4;
    const int kq = (c & 15) ^ (col & 15);
    GLOAD16(xb + (size_t)(c0 + col) * Dd + hh * 128 + kq * 8, buf + (size_t)c * 8);
  }
}

// ---------------- K1: MFMA Gram + fused masked max/min ----------------
// 8 waves x (64 rows x 32 cols) wave tiles -> 128x128 tile per ct step.
// A (64 rows x K=256 per wave) lives in 128 VGPRs; af[32]+acc[8]+pmax/nmin[32] ~= 230 regs
// fits the 256-reg budget at 2 waves/SIMD. B double-buffered in 2x32KB LDS; loads for a
// buffer are always issued one full MFMA-phase before the barrier that drains them.
__global__ __launch_bounds__(512, 2) void pairwise_kernel(const unsigned short* __restrict__ xb,
                                                          const int* __restrict__ lab,
                                                          const float* __restrict__ sq,
                                                          unsigned int* __restrict__ pos2,
                                                          unsigned int* __restrict__ neg2) {
  __shared__ __align__(16) unsigned short Us[4096 * 8];  // 64KB: A staging, then B dbuf
  __shared__ int lab_s[128];

  const int t = threadIdx.x;   // 0..511
  const int lane = t & 63;
  const int w = t >> 6;        // 0..7
  const int wr = w >> 2;       // 0..1  (row half)
  const int wc = w & 3;        // 0..3  (col quarter)
  const int c_l = lane & 15;
  const int kq_l = lane >> 4;
  const int rows0 = blockIdx.x * 128;
  const int cbase = blockIdx.y * (Nn / NSPLIT);

  // ---- stage A (both K halves) into Us, once, coalesced ----
  stage_half(xb, rows0, 0, Us, t);
  stage_half(xb, rows0, 1, Us + 2048 * 8, t);
  if (t < 128) lab_s[t] = lab[rows0 + t];
  __syncthreads();  // A staged (implicit vmcnt(0))

  // ---- A fragments -> registers for the whole kernel ----
  const short8* Uv = (const short8*)Us;
  short8 af[32];
#pragma unroll
  for (int k2 = 0; k2 < 8; ++k2)
#pragma unroll
    for (int m = 0; m < 4; ++m) {
      const int kqf = k2 * 4 + kq_l;               // global k-octet 0..31
      const int rl = wr * 64 + m * 16 + c_l;       // local row 0..127
      af[k2 * 4 + m] = Uv[(kqf >> 4) * 2048 + rl * 16 + ((kqf & 15) ^ (rl & 15))];
    }
  // row labels, packed 2 per int, hoisted for the whole kernel
  int labp[8];
#pragma unroll
  for (int m = 0; m < 4; ++m)
#pragma unroll
    for (int p = 0; p < 2; ++p) {
      const int r0 = wr * 64 + m * 16 + kq_l * 4 + 2 * p;
      labp[m * 2 + p] = (lab_s[r0] & 0xffff) | (lab_s[r0 + 1] << 16);
    }
  __syncthreads();  // all af/lab reads done before B staging overwrites Us

  unsigned short* Bs0 = Us;
  unsigned short* Bs1 = Us + 2048 * 8;
  const short8* Bv0 = (const short8*)Bs0;
  const short8* Bv1 = (const short8*)Bs1;

  stage_half(xb, cbase, 0, Bs0, t);  // prefetch first half-tile

  float pmax[16], nmin[16];
#pragma unroll
  for (int i = 0; i < 16; ++i) { pmax[i] = -INFINITY; nmin[i] = INFINITY; }

#pragma unroll 1
  for (int ct = 0; ct < 8; ++ct) {
    const int c0 = cbase + ct * 128;
    f32x4 acc[4][2];
#pragma unroll
    for (int m = 0; m < 4; ++m)
#pragma unroll
      for (int n = 0; n < 2; ++n) acc[m][n] = (f32x4){0.f, 0.f, 0.f, 0.f};

    // ---- half 0: compute Bs0, prefetch Bs1 (drained only at NEXT barrier) ----
    __syncthreads();  // Bs0 staged (loads issued one phase ago); WAR-protects Bs1
    stage_half(xb, c0, 1, Bs1, t);
#pragma unroll
    for (int ks = 0; ks < 4; ++ks) {
      short8 bf[2];
#pragma unroll
      for (int n = 0; n < 2; ++n) {
        const int cc = wc * 32 + n * 16 + c_l;
        bf[n] = Bv0[cc * 16 + ((ks * 4 + kq_l) ^ (cc & 15))];
      }
#pragma unroll
      for (int m = 0; m < 4; ++m)
#pragma unroll
        for (int n = 0; n < 2; ++n)
          acc[m][n] = __builtin_amdgcn_mfma_f32_16x16x32_bf16(af[ks * 4 + m], bf[n], acc[m][n], 0, 0, 0);
    }

    // ---- half 1: compute Bs1, prefetch next ct's Bs0 ----
    __syncthreads();  // Bs1 staged; WAR-protects Bs0
    if (ct < 7) stage_half(xb, c0 + 128, 0, Bs0, t);
#pragma unroll
    for (int ks = 0; ks < 4; ++ks) {
      short8 bf[2];
#pragma unroll
      for (int n = 0; n < 2; ++n) {
        const int cc = wc * 32 + n * 16 + c_l;
        bf[n] = Bv1[cc * 16 + ((ks * 4 + kq_l) ^ (cc & 15))];
      }
#pragma unroll
      for (int m = 0; m < 4; ++m)
#pragma unroll
        for (int n = 0; n < 2; ++n)
          acc[m][n] = __builtin_amdgcn_mfma_f32_16x16x32_bf16(af[(4 + ks) * 4 + m], bf[n], acc[m][n], 0, 0, 0);
    }

    // ---- epilogue: update running masked max/min (registers only) ----
#pragma unroll
    for (int n = 0; n < 2; ++n) {
      const int colg = c0 + wc * 32 + n * 16 + c_l;
      const float sc = sq[colg];
      const int lc = lab[colg];
#pragma unroll
      for (int idx = 0; idx < 16; ++idx) {
        const int m = idx >> 2, q = idx & 3;
        const float g = fmaf(-2.0f, acc[m][n][q], sc);
        const int lr = (labp[idx >> 1] >> ((idx & 1) * 16)) & 0xffff;
        const bool same = (lr == lc);
        pmax[idx] = same ? fmaxf(pmax[idx], g) : pmax[idx];
        nmin[idx] = same ? nmin[idx] : fminf(nmin[idx], g);
      }
    }
  }

  // ---- reduce over the 16 col-lanes, then 2 atomics per row ----
#pragma unroll
  for (int i = 0; i < 16; ++i) {
    float p = pmax[i], nn2 = nmin[i];
#pragma unroll
    for (int off = 1; off < 16; off <<= 1) {
      p = fmaxf(p, __shfl_xor(p, off));
      nn2 = fminf(nn2, __shfl_xor(nn2, off));
    }
    if (c_l == 0) {
      const int rowg = rows0 + wr * 64 + (i >> 2) * 16 + kq_l * 4 + (i & 3);
      atomicMax(&pos2[rowg], enc_ord(p));
      atomicMin(&neg2[rowg], enc_ord(nn2));
    }
  }
}

// ---------------- K2: finalize: hv, extremes, per-wave histograms, cdf, loss ----------------
__global__ __launch_bounds__(1024) void finalize_kernel(const unsigned int* __restrict__ pos2,
                                                        const unsigned int* __restrict__ neg2,
                                                        const float* __restrict__ sq,
                                                        float* __restrict__ out) {
  __shared__ float hv_s[Nn];
  __shared__ float rbuf[16];
  __shared__ float rbuf2[16];
  __shared__ float hist_w[16][NBINS];
  __shared__ float cdf_s[NBINS];
  __shared__ float s_minv, s_bw;
  const int t = threadIdx.x;
  const int lane = t & 63, wid = t >> 6;

  hist_w[wid][lane] = 0.0f;

  float lmax = -INFINITY, lmin = INFINITY;
  for (int i = t; i < Nn; i += 1024) {
    const float s = sq[i];
    const float p2 = fmaxf(s + dec_ord(pos2[i]), 1e-12f);
    const float n2 = fmaxf(s + dec_ord(neg2[i]), 1e-12f);
    const float hv = sqrtf(p2) - sqrtf(n2);
    hv_s[i] = hv;
    lmax = fmaxf(lmax, hv);
    lmin = fminf(lmin, hv);
  }
#pragma unroll
  for (int off = 32; off >= 1; off >>= 1) {
    lmax = fmaxf(lmax, __shfl_xor(lmax, off));
    lmin = fminf(lmin, __shfl_xor(lmin, off));
  }
  if (lane == 0) { rbuf[wid] = lmax; rbuf2[wid] = lmin; }
  __syncthreads();
  if (t == 0) {
    float gmax = rbuf[0], gmin = rbuf2[0];
    for (int w = 1; w < 16; ++w) { gmax = fmaxf(gmax, rbuf[w]); gmin = fminf(gmin, rbuf2[w]); }
    const float maxv = fmaxf(gmax, 2.0f);
    const float minv = fminf(gmin, -2.0f);
    s_minv = minv;
    s_bw = (maxv - minv) / (float)(NBINS - 1);
  }
  __syncthreads();

  const float minv = s_minv, bw = s_bw;
  for (int i = t; i < Nn; i += 1024) {
    const float hv = hv_s[i];
    int lo = (int)floorf((hv - minv) / bw);
    lo = min(max(lo, 0), NBINS - 1);
    const int hi = min(lo + 1, NBINS - 1);
    const float alpha = 1.0f - (hv - minv - (float)lo * bw) / bw;
    atomicAdd(&hist_w[wid][lo], alpha);
    atomicAdd(&hist_w[wid][hi], 1.0f - alpha);
  }
  __syncthreads();

  if (t < NBINS) {
    float h = 0.0f;
#pragma unroll
    for (int w2 = 0; w2 < 16; ++w2) h += hist_w[w2][t];
    float total = h;
#pragma unroll
    for (int off = 32; off >= 1; off >>= 1) total += __shfl_xor(total, off);
    const float hn = h / (total + 1e-6f);
    float s2 = hn;
#pragma unroll
    for (int off = 32; off >= 1; off >>= 1) s2 += __shfl_xor(s2, off);
    const float pdf = hn / s2;
    float c = pdf;
#pragma unroll
    for (int off = 1; off < 64; off <<= 1) {
      const float u = __shfl_up(c, off);
      if (lane >= off) c += u;
    }
    cdf_s[t] = c;
  }
  __syncthreads();

  float acc = 0.0f;
  for (int i = t; i < Nn; i += 1024) {
    const float hv = hv_s[i];
    int lo = (int)floorf((hv - minv) / bw);
    lo = min(max(lo, 0), NBINS - 1);
    acc += cdf_s[lo] * hv;
  }
#pragma unroll
  for (int off = 32; off >= 1; off >>= 1) acc += __shfl_xor(acc, off);
  if (lane == 0) rbuf[wid] = acc;
  __syncthreads();
  if (t == 0) {
    float s = 0.0f;
    for (int w2 = 0; w2 < 16; ++w2) s += rbuf[w2];
    out[0] = s / (float)Nn;
  }
}

// ---------------- launch ----------------
extern "C" void kernel_launch(void* const* d_in, const int* in_sizes, int n_in,
                              void* d_out, int out_size, void* d_ws, size_t ws_size,
                              hipStream_t stream) {
  const float* x = (const float*)d_in[0];
  const int* targets = (const int*)d_in[1];
  float* out = (float*)d_out;

  unsigned short* xb = (unsigned short*)d_ws;  // 4 MB
  char* p = (char*)d_ws + (size_t)Nn * Dd * sizeof(unsigned short);
  float* sq = (float*)p;
  unsigned int* pos2 = (unsigned int*)(p + (size_t)Nn * sizeof(float));
  unsigned int* neg2 = (unsigned int*)(p + 2 * (size_t)Nn * sizeof(float));

  prep_kernel<<<Nn / 4, 256, 0, stream>>>(x, xb, sq, pos2, neg2);
  pairwise_kernel<<<dim3(Nn / 128, NSPLIT), 512, 0, stream>>>(xb, targets, sq, pos2, neg2);
  finalize_kernel<<<1, 1024, 0, stream>>>(pos2, neg2, sq, out);
}